// Round 5
// baseline (26333.521 us; speedup 1.0000x reference)
//
#include <hip/hip_runtime.h>

#define BB 256
#define TT 1024
#define DDIM 6
#define HH 256
#define AGSCOPE __HIP_MEMORY_SCOPE_AGENT

typedef float f4 __attribute__((ext_vector_type(4)));
typedef float f2 __attribute__((ext_vector_type(2)));

// grid: 256 blocks = 8 batch-groups (bg = blk & 7) x 32 unit-groups (gg = blk >> 3)
// block: 256 threads, two roles:
//   dot role:   tid = dg*64 + db4*8 + dul  -> gate dg (0..3), batch-quad db4
//               (4 rows), unit-sub dul (0..7). Each thread: 1 gate x 4 batches
//               x 256-dot  => one ds_read_b128 weight quad feeds 16 MACs (4x
//               LDS-pipe reduction vs R4 — the measured bottleneck).
//   owner role: tid = b_l*8 + ul -> (batch b, unit) state: c1,c2, nonlins,
//               x-part, h stores. Gates exchanged dot->owner via gl[] in LDS.
// ws: flags[256] @0 | h1g[2][256][256] f32 @1024 | h2g[2][256][256] @525312
// Exchange protocol (R3/R4-proven): relaxed agent stores (write-through),
// flag publish, poll + one acquire (buffer_inv) per WG per step.

__device__ __forceinline__ float sigf(float x) {
    return __builtin_amdgcn_rcpf(1.0f + __expf(-x));
}
__device__ __forceinline__ float tanhf_fast(float x) {
    return fmaf(2.0f, __builtin_amdgcn_rcpf(1.0f + __expf(-2.0f * x)), -1.0f);
}
__device__ __forceinline__ void st_agent(float* p, float v) {
    __hip_atomic_store(p, v, __ATOMIC_RELAXED, AGSCOPE);
}

__device__ __forceinline__ void group_barrier(int* flags, int bg, int token) {
    __syncthreads();                      // drains vmcnt -> h stores at L3
    asm volatile("" ::: "memory");
    if (threadIdx.x == 0) {
        __hip_atomic_store(&flags[blockIdx.x], token, __ATOMIC_RELAXED, AGSCOPE);
    }
    if (threadIdx.x < 32) {               // poll the 32 peers of this group
        while (__hip_atomic_load(&flags[bg + 8 * (int)threadIdx.x], __ATOMIC_RELAXED,
                                 AGSCOPE) < token) {
            __builtin_amdgcn_s_sleep(2);
        }
    }
    if (threadIdx.x == 0) {               // one buffer_inv per block per step
        (void)__hip_atomic_load(&flags[blockIdx.x], __ATOMIC_ACQUIRE, AGSCOPE);
    }
    __syncthreads();
    asm volatile("" ::: "memory");
}

// 1 weight row (64 quads from LDS) x 4 batch h-streams (global), f2-packed.
// Each ds_read_b128 (weight quad) feeds 8 pk-FMAs (4 batches x 2).
__device__ __forceinline__ void dot4b(const float* __restrict__ hbase,
                                      const f4* __restrict__ wr,
                                      f2 (&A)[4])
{
    const f4* h0 = (const f4*)(hbase);
    const f4* h1 = (const f4*)(hbase + HH);
    const f4* h2 = (const f4*)(hbase + 2 * HH);
    const f4* h3 = (const f4*)(hbase + 3 * HH);
    #pragma unroll 4
    for (int c = 0; c < 64; ++c) {
        const f4 w = wr[c];
        const f2 wl = w.xy, wh = w.zw;
        f4 h;
        h = h0[c];
        A[0] = __builtin_elementwise_fma(h.xy, wl, A[0]);
        A[0] = __builtin_elementwise_fma(h.zw, wh, A[0]);
        h = h1[c];
        A[1] = __builtin_elementwise_fma(h.xy, wl, A[1]);
        A[1] = __builtin_elementwise_fma(h.zw, wh, A[1]);
        h = h2[c];
        A[2] = __builtin_elementwise_fma(h.xy, wl, A[2]);
        A[2] = __builtin_elementwise_fma(h.zw, wh, A[2]);
        h = h3[c];
        A[3] = __builtin_elementwise_fma(h.xy, wl, A[3]);
        A[3] = __builtin_elementwise_fma(h.zw, wh, A[3]);
    }
}

__device__ __forceinline__ void emit_out(const float* __restrict__ h2row,
                                         const float (*Wo)[256],
                                         float (*redsc)[8],
                                         float boV,
                                         float* __restrict__ op, int tid) {
    const float hval = h2row[tid];
    float p0 = Wo[0][tid] * hval;
    float p1 = Wo[1][tid] * hval;
    float p2 = Wo[2][tid] * hval;
    float p3 = Wo[3][tid] * hval;
    float p4 = Wo[4][tid] * hval;
    float p5 = Wo[5][tid] * hval;
    #pragma unroll
    for (int off = 1; off < 64; off <<= 1) {
        p0 += __shfl_xor(p0, off);
        p1 += __shfl_xor(p1, off);
        p2 += __shfl_xor(p2, off);
        p3 += __shfl_xor(p3, off);
        p4 += __shfl_xor(p4, off);
        p5 += __shfl_xor(p5, off);
    }
    const int wid = tid >> 6;
    if ((tid & 63) == 0) {
        redsc[wid][0] = p0; redsc[wid][1] = p1; redsc[wid][2] = p2;
        redsc[wid][3] = p3; redsc[wid][4] = p4; redsc[wid][5] = p5;
    }
    __syncthreads();
    if (tid < 6) {
        op[tid] = redsc[0][tid] + redsc[1][tid] + redsc[2][tid] + redsc[3][tid] + boV;
    }
}

__global__ __launch_bounds__(256, 1) void lstm_persist(
    const float* __restrict__ x,
    const float* __restrict__ W_ih1, const float* __restrict__ W_hh1,
    const float* __restrict__ b_ih1, const float* __restrict__ b_hh1,
    const float* __restrict__ W_ih2, const float* __restrict__ W_hh2,
    const float* __restrict__ b_ih2, const float* __restrict__ b_hh2,
    const float* __restrict__ W_out, const float* __restrict__ b_out,
    float* __restrict__ out,
    int* __restrict__ flags, float* __restrict__ h1g, float* __restrict__ h2g)
{
    // weight rows: stride 260/516 floats -> 1 bank step per row; dword-phased
    // b128 reads of rows {dg*8+dul} are conflict-free (verified R3: 0 conflicts).
    __shared__ float L1w[32][260];   // cols 0..255 = W_hh1 row
    __shared__ float Wx1[32][8];     // cols 0..5   = W_ih1 row
    __shared__ float L2w[32][516];   // 0..255 = W_ih2 (h1 in), 256..511 = W_hh2 (h2 in)
    __shared__ float Wo[6][256];
    __shared__ float redsc[4][8];
    __shared__ float gl[32][36];     // gate exchange [gate*8+ul][b_l], pad 36

    const int tid = threadIdx.x;
    const int bg  = blockIdx.x & 7;        // batch-group
    const int gg  = blockIdx.x >> 3;       // unit-group
    // dot role
    const int dg   = tid >> 6;             // gate 0..3 (wave = gate)
    const int db4  = (tid >> 3) & 7;       // batch-quad 0..7
    const int dul  = tid & 7;              // unit-sub 0..7
    const int drow = (dg << 3) + dul;      // LDS weight row
    const int db0  = (bg << 5) + (db4 << 2); // first of 4 batch rows
    // owner role
    const int b_l = tid >> 3;
    const int ul  = tid & 7;
    const int unit = (gg << 3) + ul;
    const int b    = (bg << 5) + b_l;
    const int ro   = (bg << 5) + gg;

    for (int rl = 0; rl < 32; ++rl) {
        const int g  = rl >> 3;
        const int u2 = rl & 7;
        const int gr = g * HH + (gg << 3) + u2;   // global gate row
        L1w[rl][tid]       = W_hh1[gr * HH + tid];
        if (tid < DDIM) Wx1[rl][tid] = W_ih1[gr * DDIM + tid];
        L2w[rl][tid]       = W_ih2[gr * HH + tid];
        L2w[rl][256 + tid] = W_hh2[gr * HH + tid];
    }
    for (int i = tid; i < 6 * 256; i += 256) Wo[i >> 8][i & 255] = W_out[i];

    float b1a[4], b2a[4];
    #pragma unroll
    for (int g = 0; g < 4; ++g) {
        const int gr = g * HH + unit;
        b1a[g] = b_ih1[gr] + b_hh1[gr];
        b2a[g] = b_ih2[gr] + b_hh2[gr];
    }
    const float boV = (tid < 6) ? b_out[tid] : 0.0f;
    __syncthreads();

    const f4* w1r = (const f4*)&L1w[drow][0];   // 64 quads
    const f4* w2r = (const f4*)&L2w[drow][0];   // quads 0..63 h1-in, 64..127 h2-in

    float c1 = 0.0f, c2 = 0.0f;

    #pragma unroll 1
    for (int t = 0; t < TT; ++t) {
        const int cur = t & 1, prv = cur ^ 1;

        // ---- Phase A (dot role): layer-1 gate partials for 4 batches ----
        {
            f2 A[4] = {{0.f,0.f},{0.f,0.f},{0.f,0.f},{0.f,0.f}};
            dot4b(h1g + prv * (BB * HH) + db0 * HH, w1r, A);
            f4 gv = { A[0].x + A[0].y, A[1].x + A[1].y,
                      A[2].x + A[2].y, A[3].x + A[3].y };
            *(f4*)&gl[drow][db4 << 2] = gv;
        }
        __syncthreads();

        // ---- Phase B (owner role): assemble layer-1 gates, update c1, h1 ----
        {
            const float* xp = x + b * (TT * DDIM) + t * DDIM;
            const float xv0 = xp[0], xv1 = xp[1], xv2 = xp[2];
            const float xv3 = xp[3], xv4 = xp[4], xv5 = xp[5];
            float gate[4];
            #pragma unroll
            for (int g = 0; g < 4; ++g) {
                const int r = (g << 3) + ul;
                float a = b1a[g] + gl[r][b_l];
                a = fmaf(Wx1[r][0], xv0, a); a = fmaf(Wx1[r][1], xv1, a);
                a = fmaf(Wx1[r][2], xv2, a); a = fmaf(Wx1[r][3], xv3, a);
                a = fmaf(Wx1[r][4], xv4, a); a = fmaf(Wx1[r][5], xv5, a);
                gate[g] = a;
            }
            const float i1 = sigf(gate[0]), f1 = sigf(gate[1]);
            const float g1 = tanhf_fast(gate[2]), o1 = sigf(gate[3]);
            c1 = fmaf(f1, c1, i1 * g1);
            const float h1v = o1 * tanhf_fast(c1);
            st_agent(&h1g[cur * (BB * HH) + b * HH + unit], h1v);
        }

        // publish h1(t); h2(t-1) stores (pre-arrival) publish too
        group_barrier(flags, bg, t + 1);

        // out(t-1) from h2(t-1) (published at this barrier)
        if (t > 0) {
            const float* h2row = h2g + ((t - 1) & 1) * (BB * HH) + ro * HH;
            emit_out(h2row, Wo, redsc, boV, out + ro * (TT * DDIM) + (t - 1) * DDIM, tid);
        }

        // ---- Phase E (dot role): layer-2 gate partials (h1(t) and h2(t-1)) ----
        {
            f2 E[4] = {{0.f,0.f},{0.f,0.f},{0.f,0.f},{0.f,0.f}};
            dot4b(h1g + cur * (BB * HH) + db0 * HH, w2r, E);
            dot4b(h2g + prv * (BB * HH) + db0 * HH, w2r + 64, E);
            f4 ev = { E[0].x + E[0].y, E[1].x + E[1].y,
                      E[2].x + E[2].y, E[3].x + E[3].y };
            *(f4*)&gl[drow][db4 << 2] = ev;
        }
        __syncthreads();

        // ---- Phase F (owner role): assemble layer-2 gates, update c2, h2 ----
        {
            float gate[4];
            #pragma unroll
            for (int g = 0; g < 4; ++g) {
                gate[g] = b2a[g] + gl[(g << 3) + ul][b_l];
            }
            const float i2 = sigf(gate[0]), f2v = sigf(gate[1]);
            const float g2 = tanhf_fast(gate[2]), o2 = sigf(gate[3]);
            c2 = fmaf(f2v, c2, i2 * g2);
            const float h2v = o2 * tanhf_fast(c2);
            st_agent(&h2g[cur * (BB * HH) + b * HH + unit], h2v);
        }
        __syncthreads();   // gl WAR guard before next step's Phase A
    }

    group_barrier(flags, bg, TT + 1);
    {
        const float* h2row = h2g + ((TT - 1) & 1) * (BB * HH) + ro * HH;
        emit_out(h2row, Wo, redsc, boV, out + ro * (TT * DDIM) + (TT - 1) * DDIM, tid);
    }
}

extern "C" void kernel_launch(void* const* d_in, const int* in_sizes, int n_in,
                              void* d_out, int out_size, void* d_ws, size_t ws_size,
                              hipStream_t stream) {
    (void)in_sizes; (void)n_in; (void)out_size; (void)ws_size;
    const float* x     = (const float*)d_in[0];
    const float* W_ih1 = (const float*)d_in[1];
    const float* W_hh1 = (const float*)d_in[2];
    const float* b_ih1 = (const float*)d_in[3];
    const float* b_hh1 = (const float*)d_in[4];
    const float* W_ih2 = (const float*)d_in[5];
    const float* W_hh2 = (const float*)d_in[6];
    const float* b_ih2 = (const float*)d_in[7];
    const float* b_hh2 = (const float*)d_in[8];
    const float* W_out = (const float*)d_in[9];
    const float* b_out = (const float*)d_in[10];
    float* out = (float*)d_out;

    char* ws = (char*)d_ws;
    int*   flags = (int*)ws;                  // 256 * 4 B
    float* h1g   = (float*)(ws + 1024);       // 2*256*256 f32
    float* h2g   = (float*)(ws + 525312);     // 2*256*256 f32

    hipMemsetAsync(d_ws, 0, 1049600, stream);

    hipLaunchKernelGGL(lstm_persist, dim3(256), dim3(256), 0, stream,
                       x, W_ih1, W_hh1, b_ih1, b_hh1,
                       W_ih2, W_hh2, b_ih2, b_hh2,
                       W_out, b_out, out, flags, h1g, h2g);
}

// Round 6
// 9612.850 us; speedup vs baseline: 2.7394x; 2.7394x over previous
//
#include <hip/hip_runtime.h>

#define BB 256
#define TT 1024
#define DDIM 6
#define HH 256
#define HP 264   // padded unit-pitch (ushorts) for bf16 h arrays: 528B rows, 16B-aligned, banks spread
#define AGSCOPE __HIP_MEMORY_SCOPE_AGENT

typedef float  f4v __attribute__((ext_vector_type(4)));
typedef float  f2v __attribute__((ext_vector_type(2)));
typedef short  s8v __attribute__((ext_vector_type(8)));
typedef unsigned int u2v __attribute__((ext_vector_type(2)));

// grid: 256 blocks = 8 batch-groups (bg = blk&7, 32 batches) x 32 unit-groups (gg = blk>>3, 8 units)
// block: 256 threads = 4 waves; wave wid=(gh,bh): C-tile rows 16gh..+15 (rows = ulocal*4+gate,
//   unit-major) x batches 16bh..+15. A (weights) = bf16 hi/lo frags in VGPRs (preconverted once).
//   B (h) = bf16 hi/lo in LDS [batch][unit] (k-contiguous == native frag order, 1 ds_read_b128/frag).
// D-layout (verified m89): col=lane&15 (batch), row=(lane>>4)*4+reg -> lane owns all 4 gates of one
//   (unit,batch): c1/c2 state and nonlinearities are lane-local.
// h exchange across WGs: f32 agent-scope stores + flag barrier (R3/R4-proven protocol).

__device__ __forceinline__ float sigf(float x) {
    return __builtin_amdgcn_rcpf(1.0f + __expf(-x));
}
__device__ __forceinline__ float tanhf_fast(float x) {
    return fmaf(2.0f, __builtin_amdgcn_rcpf(1.0f + __expf(-2.0f * x)), -1.0f);
}
__device__ __forceinline__ void st_agent(float* p, float v) {
    __hip_atomic_store(p, v, __ATOMIC_RELAXED, AGSCOPE);
}
__device__ __forceinline__ unsigned int pk2(unsigned short a, unsigned short b) {
    return (unsigned int)a | ((unsigned int)b << 16);
}

#define MFMA(a, b, c) __builtin_amdgcn_mfma_f32_16x16x32_bf16(a, b, c, 0, 0, 0)

// f32 -> bf16 hi (RNE) + bf16 lo (RNE of residual)
__device__ __forceinline__ void cvt_hl(float v, unsigned short& hi, unsigned short& lo) {
    unsigned int u = __float_as_uint(v);
    unsigned int r = (u + 0x7fffu + ((u >> 16) & 1u)) & 0xffff0000u;
    hi = (unsigned short)(r >> 16);
    float lof = v - __uint_as_float(r);
    unsigned int u2 = __float_as_uint(lof);
    lo = (unsigned short)((u2 + 0x7fffu + ((u2 >> 16) & 1u)) >> 16);
}

__device__ __forceinline__ void pack8_hl(const float* __restrict__ p, s8v& hi, s8v& lo) {
    #pragma unroll
    for (int j = 0; j < 8; ++j) {
        unsigned short h, l;
        cvt_hl(p[j], h, l);
        hi[j] = (short)h;
        lo[j] = (short)l;
    }
}

__device__ __forceinline__ void group_barrier(int* flags, int bg, int token) {
    __syncthreads();                      // drains vmcnt -> h stores at L3
    asm volatile("" ::: "memory");
    if (threadIdx.x == 0) {
        __hip_atomic_store(&flags[blockIdx.x], token, __ATOMIC_RELAXED, AGSCOPE);
    }
    if (threadIdx.x < 32) {
        while (__hip_atomic_load(&flags[bg + 8 * (int)threadIdx.x], __ATOMIC_RELAXED,
                                 AGSCOPE) < token) {
            __builtin_amdgcn_s_sleep(2);
        }
    }
    if (threadIdx.x == 0) {               // one buffer_inv per block per step
        (void)__hip_atomic_load(&flags[blockIdx.x], __ATOMIC_ACQUIRE, AGSCOPE);
    }
    __syncthreads();
    asm volatile("" ::: "memory");
}

__device__ __forceinline__ void emit_out(const float* __restrict__ h2row,
                                         const float (*Wo)[256],
                                         float (*redsc)[8],
                                         float boV,
                                         float* __restrict__ op, int tid) {
    const float hval = h2row[tid];
    float p0 = Wo[0][tid] * hval;
    float p1 = Wo[1][tid] * hval;
    float p2 = Wo[2][tid] * hval;
    float p3 = Wo[3][tid] * hval;
    float p4 = Wo[4][tid] * hval;
    float p5 = Wo[5][tid] * hval;
    #pragma unroll
    for (int off = 1; off < 64; off <<= 1) {
        p0 += __shfl_xor(p0, off);
        p1 += __shfl_xor(p1, off);
        p2 += __shfl_xor(p2, off);
        p3 += __shfl_xor(p3, off);
        p4 += __shfl_xor(p4, off);
        p5 += __shfl_xor(p5, off);
    }
    const int wid = tid >> 6;
    if ((tid & 63) == 0) {
        redsc[wid][0] = p0; redsc[wid][1] = p1; redsc[wid][2] = p2;
        redsc[wid][3] = p3; redsc[wid][4] = p4; redsc[wid][5] = p5;
    }
    __syncthreads();
    if (tid < 6) {
        op[tid] = redsc[0][tid] + redsc[1][tid] + redsc[2][tid] + redsc[3][tid] + boV;
    }
}

__global__ __launch_bounds__(256, 1) void lstm_persist(
    const float* __restrict__ x,
    const float* __restrict__ W_ih1, const float* __restrict__ W_hh1,
    const float* __restrict__ b_ih1, const float* __restrict__ b_hh1,
    const float* __restrict__ W_ih2, const float* __restrict__ W_hh2,
    const float* __restrict__ b_ih2, const float* __restrict__ b_hh2,
    const float* __restrict__ W_out, const float* __restrict__ b_out,
    float* __restrict__ out,
    int* __restrict__ flags, float* __restrict__ h1g, float* __restrict__ h2g)
{
    __shared__ unsigned short h1hi[32][HP], h1lo[32][HP];   // h1(t-1)/h1(t) bf16, [batch][unit]
    __shared__ unsigned short h2hi[32][HP], h2lo[32][HP];   // h2(t-1) bf16
    __shared__ float Wo[6][256];
    __shared__ float redsc[4][8];
    __shared__ float guard[2048];   // LDS occupancy guard: total >80KB -> 1 block/CU

    const int tid = threadIdx.x;
    const int bg  = blockIdx.x & 7;
    const int gg  = blockIdx.x >> 3;
    const int wid = tid >> 6;
    const int l   = tid & 63;
    const int gh  = wid >> 1;              // gate-row-half (unit half)
    const int bh  = wid & 1;               // batch half
    const int kl  = (l >> 4) << 3;         // lane k-offset within 32-chunk (A and B)
    // A-operand lane: row r32 = gh*16 + (l&15), row = ulocal*4 + gate
    const int r32  = (gh << 4) + (l & 15);
    const int gr_a = (r32 & 3) * HH + (gg << 3) + (r32 >> 2);   // global gate row
    // D-owner lane: unit du, batch db
    const int du      = (gh << 2) + (l >> 4);
    const int db      = (bh << 4) + (l & 15);
    const int unit_abs = (gg << 3) + du;
    const int db_abs   = (bg << 5) + db;
    const int ro       = (bg << 5) + gg;   // batch row whose `out` this WG emits

    // ---- prologue: zero frag arrays, load Wo ----
    for (int i = tid; i < (32 * HP) / 2; i += 256) {
        ((unsigned int*)h1hi)[i] = 0u;
        ((unsigned int*)h1lo)[i] = 0u;
        ((unsigned int*)h2hi)[i] = 0u;
        ((unsigned int*)h2lo)[i] = 0u;
    }
    for (int i = tid; i < 2048; i += 256) guard[i] = 0.0f;
    for (int i = tid; i < 6 * 256; i += 256) Wo[i >> 8][i & 255] = W_out[i];

    // ---- A-fragments: W rows -> bf16 hi/lo in VGPRs (one-time) ----
    s8v A1h[8], A1l[8], A2h[16], A2l[16];
    {
        const float* w1 = W_hh1 + gr_a * HH;
        #pragma unroll
        for (int c = 0; c < 8; ++c) pack8_hl(w1 + c * 32 + kl, A1h[c], A1l[c]);
        const float* w2i = W_ih2 + gr_a * HH;
        #pragma unroll
        for (int c = 0; c < 8; ++c) pack8_hl(w2i + c * 32 + kl, A2h[c], A2l[c]);
        const float* w2h = W_hh2 + gr_a * HH;
        #pragma unroll
        for (int c = 0; c < 8; ++c) pack8_hl(w2h + c * 32 + kl, A2h[8 + c], A2l[8 + c]);
    }

    // ---- D-owner constants: biases + x-weights in regs ----
    float b1a[4], b2a[4], Wxr[4][6];
    #pragma unroll
    for (int g = 0; g < 4; ++g) {
        const int gr = g * HH + unit_abs;
        b1a[g] = b_ih1[gr] + b_hh1[gr];
        b2a[g] = b_ih2[gr] + b_hh2[gr];
        #pragma unroll
        for (int d = 0; d < 6; ++d) Wxr[g][d] = W_ih1[gr * DDIM + d];
    }
    const float boV = (tid < 6) ? b_out[tid] : 0.0f;
    float c1 = 0.0f, c2 = 0.0f;
    __syncthreads();

    #pragma unroll 1
    for (int t = 0; t < TT; ++t) {
        const int cur = t & 1, prv = cur ^ 1;

        // ---- P1: layer-1 MFMAs (B = h1(t-1) frags from LDS) ----
        const float* xp = x + (size_t)db_abs * (TT * DDIM) + t * DDIM;
        const f2v xA = *(const f2v*)(xp);
        const f2v xB = *(const f2v*)(xp + 2);
        const f2v xC = *(const f2v*)(xp + 4);

        f4v acc = {0.f, 0.f, 0.f, 0.f};
        #pragma unroll
        for (int c = 0; c < 8; ++c) {
            const s8v bhi = *(const s8v*)&h1hi[db][c * 32 + kl];
            const s8v blo = *(const s8v*)&h1lo[db][c * 32 + kl];
            acc = MFMA(A1h[c], bhi, acc);
            acc = MFMA(A1h[c], blo, acc);
            acc = MFMA(A1l[c], bhi, acc);
        }
        {
            float ga[4];
            #pragma unroll
            for (int g = 0; g < 4; ++g) {
                float a = acc[g] + b1a[g];
                a = fmaf(Wxr[g][0], xA.x, a); a = fmaf(Wxr[g][1], xA.y, a);
                a = fmaf(Wxr[g][2], xB.x, a); a = fmaf(Wxr[g][3], xB.y, a);
                a = fmaf(Wxr[g][4], xC.x, a); a = fmaf(Wxr[g][5], xC.y, a);
                ga[g] = a;
            }
            const float i1 = sigf(ga[0]), f1 = sigf(ga[1]);
            const float g1 = tanhf_fast(ga[2]), o1 = sigf(ga[3]);
            c1 = fmaf(f1, c1, i1 * g1);
            const float h1v = o1 * tanhf_fast(c1);
            st_agent(&h1g[cur * (BB * HH) + db_abs * HH + unit_abs], h1v);
        }

        // publish h1(t); h2(t-1) stores (pre-arrival, last iter) publish too
        group_barrier(flags, bg, t + 1);

        // ---- CONV loads issued first (overlap emit), then emit, then cvt+store ----
        const int cb = tid >> 3, cu0 = (tid & 7) << 5;
        const float* s1 = h1g + cur * (BB * HH) + ((bg << 5) + cb) * HH + cu0;
        const float* s2 = h2g + prv * (BB * HH) + ((bg << 5) + cb) * HH + cu0;
        f4v v1[8], v2[8];
        #pragma unroll
        for (int i = 0; i < 8; ++i) v1[i] = ((const f4v*)s1)[i];
        #pragma unroll
        for (int i = 0; i < 8; ++i) v2[i] = ((const f4v*)s2)[i];

        if (t > 0) {
            const float* h2row = h2g + prv * (BB * HH) + ro * HH;
            emit_out(h2row, Wo, redsc, boV, out + ro * (TT * DDIM) + (t - 1) * DDIM, tid);
        }

        {
            unsigned short* d1h = &h1hi[cb][cu0];
            unsigned short* d1l = &h1lo[cb][cu0];
            unsigned short* d2h = &h2hi[cb][cu0];
            unsigned short* d2l = &h2lo[cb][cu0];
            #pragma unroll
            for (int i = 0; i < 8; ++i) {
                unsigned short hA, lA, hB, lB, hC, lC, hD, lD;
                cvt_hl(v1[i][0], hA, lA); cvt_hl(v1[i][1], hB, lB);
                cvt_hl(v1[i][2], hC, lC); cvt_hl(v1[i][3], hD, lD);
                u2v wh; wh[0] = pk2(hA, hB); wh[1] = pk2(hC, hD);
                u2v wl; wl[0] = pk2(lA, lB); wl[1] = pk2(lC, lD);
                *(u2v*)&d1h[4 * i] = wh;
                *(u2v*)&d1l[4 * i] = wl;
            }
            #pragma unroll
            for (int i = 0; i < 8; ++i) {
                unsigned short hA, lA, hB, lB, hC, lC, hD, lD;
                cvt_hl(v2[i][0], hA, lA); cvt_hl(v2[i][1], hB, lB);
                cvt_hl(v2[i][2], hC, lC); cvt_hl(v2[i][3], hD, lD);
                u2v wh; wh[0] = pk2(hA, hB); wh[1] = pk2(hC, hD);
                u2v wl; wl[0] = pk2(lA, lB); wl[1] = pk2(lC, lD);
                *(u2v*)&d2h[4 * i] = wh;
                *(u2v*)&d2l[4 * i] = wl;
            }
        }
        __syncthreads();

        // ---- P5: layer-2 MFMAs (B = [h1(t); h2(t-1)] frags) ----
        f4v acc2 = {0.f, 0.f, 0.f, 0.f};
        #pragma unroll
        for (int c = 0; c < 8; ++c) {
            const s8v bhi = *(const s8v*)&h1hi[db][c * 32 + kl];
            const s8v blo = *(const s8v*)&h1lo[db][c * 32 + kl];
            acc2 = MFMA(A2h[c], bhi, acc2);
            acc2 = MFMA(A2h[c], blo, acc2);
            acc2 = MFMA(A2l[c], bhi, acc2);
        }
        #pragma unroll
        for (int c = 0; c < 8; ++c) {
            const s8v bhi = *(const s8v*)&h2hi[db][c * 32 + kl];
            const s8v blo = *(const s8v*)&h2lo[db][c * 32 + kl];
            acc2 = MFMA(A2h[8 + c], bhi, acc2);
            acc2 = MFMA(A2h[8 + c], blo, acc2);
            acc2 = MFMA(A2l[8 + c], bhi, acc2);
        }
        {
            const float i2 = sigf(acc2[0] + b2a[0]);
            const float f2g = sigf(acc2[1] + b2a[1]);
            const float g2 = tanhf_fast(acc2[2] + b2a[2]);
            const float o2 = sigf(acc2[3] + b2a[3]);
            c2 = fmaf(f2g, c2, i2 * g2);
            const float h2v = o2 * tanhf_fast(c2);
            st_agent(&h2g[cur * (BB * HH) + db_abs * HH + unit_abs], h2v);
        }
    }

    group_barrier(flags, bg, TT + 1);
    {
        const float* h2row = h2g + ((TT - 1) & 1) * (BB * HH) + ro * HH;
        emit_out(h2row, Wo, redsc, boV, out + ro * (TT * DDIM) + (TT - 1) * DDIM, tid);
    }
    // keep-alive for guard[] (condition is always false at runtime, opaque to compiler)
    if (b_out[0] > 1e30f) out[ro * (TT * DDIM)] += guard[tid & 2047];
}

extern "C" void kernel_launch(void* const* d_in, const int* in_sizes, int n_in,
                              void* d_out, int out_size, void* d_ws, size_t ws_size,
                              hipStream_t stream) {
    (void)in_sizes; (void)n_in; (void)out_size; (void)ws_size;
    const float* x     = (const float*)d_in[0];
    const float* W_ih1 = (const float*)d_in[1];
    const float* W_hh1 = (const float*)d_in[2];
    const float* b_ih1 = (const float*)d_in[3];
    const float* b_hh1 = (const float*)d_in[4];
    const float* W_ih2 = (const float*)d_in[5];
    const float* W_hh2 = (const float*)d_in[6];
    const float* b_ih2 = (const float*)d_in[7];
    const float* b_hh2 = (const float*)d_in[8];
    const float* W_out = (const float*)d_in[9];
    const float* b_out = (const float*)d_in[10];
    float* out = (float*)d_out;

    char* ws = (char*)d_ws;
    int*   flags = (int*)ws;                  // 256 * 4 B
    float* h1g   = (float*)(ws + 1024);       // 2*256*256 f32
    float* h2g   = (float*)(ws + 525312);     // 2*256*256 f32

    hipMemsetAsync(d_ws, 0, 1049600, stream);

    hipLaunchKernelGGL(lstm_persist, dim3(256), dim3(256), 0, stream,
                       x, W_ih1, W_hh1, b_ih1, b_hh1,
                       W_ih2, W_hh2, b_ih2, b_hh2,
                       W_out, b_out, out, flags, h1g, h2g);
}

// Round 7
// 7618.768 us; speedup vs baseline: 3.4564x; 1.2617x over previous
//
#include <hip/hip_runtime.h>

#define BB 256
#define TT 1024
#define DDIM 6
#define HH 256
#define AGSCOPE __HIP_MEMORY_SCOPE_AGENT

typedef float  f4v __attribute__((ext_vector_type(4)));
typedef float  f2v __attribute__((ext_vector_type(2)));
typedef short  s8v __attribute__((ext_vector_type(8)));
typedef unsigned int u32;

// grid: 256 blocks = 8 batch-groups (bg = blk&7, 32 batches) x 32 unit-groups (gg = blk>>3, 8 units)
// block: 4 waves; wave (gh,bh): C rows 16gh..+15 (row = ulocal*4+gate) x batches 16bh..+15.
// A (weights) bf16 hi/lo frags live in VGPRs (converted once). B (h) bf16 hi/lo lives in LDS in
// FRAG-LINEAR layout: for half bh, chunk c, lane l, the 16B at [bh][c][l] holds
// h[b=(l&15)][k=c*32+(l>>4)*8+j] -> every ds_read_b128 is a linear 1KB wave block (0 conflicts),
// and global->LDS staging is an identity copy via global_load_lds_dwordx4.
// Global bf16 arrays use the same swizzle: soff(b,k) = (k>>5)*512+((k>>3)&3)*128+(b&15)*8+(k&7)
// in a [dbuf][bg][half][4096 u16] array. Owners write h once (hi,lo agent stores); no f32 h at all.
// Exchange protocol (R3/R4/R6-proven): relaxed agent stores + flag barrier + one acquire/WG/step.

__device__ __forceinline__ float sigf(float x) {
    return __builtin_amdgcn_rcpf(1.0f + __expf(-x));
}
__device__ __forceinline__ float tanhf_fast(float x) {
    return fmaf(2.0f, __builtin_amdgcn_rcpf(1.0f + __expf(-2.0f * x)), -1.0f);
}
__device__ __forceinline__ void st_agent_u16(unsigned short* p, unsigned short v) {
    __hip_atomic_store(p, v, __ATOMIC_RELAXED, AGSCOPE);
}

#define MFMA(a, b, c) __builtin_amdgcn_mfma_f32_16x16x32_bf16(a, b, c, 0, 0, 0)

// f32 -> bf16 hi (RNE) + bf16 lo (RNE of residual)
__device__ __forceinline__ void cvt_hl(float v, unsigned short& hi, unsigned short& lo) {
    u32 u = __float_as_uint(v);
    u32 r = (u + 0x7fffu + ((u >> 16) & 1u)) & 0xffff0000u;
    hi = (unsigned short)(r >> 16);
    float lof = v - __uint_as_float(r);
    u32 u2 = __float_as_uint(lof);
    lo = (unsigned short)((u2 + 0x7fffu + ((u2 >> 16) & 1u)) >> 16);
}

__device__ __forceinline__ void pack8_hl(const float* __restrict__ p, s8v& hi, s8v& lo) {
    #pragma unroll
    for (int j = 0; j < 8; ++j) {
        unsigned short h, l;
        cvt_hl(p[j], h, l);
        hi[j] = (short)h;
        lo[j] = (short)l;
    }
}

// async 16B/lane global->LDS copy (lds dest wave-uniform; HW adds lane*16)
__device__ __forceinline__ void stage16(const unsigned short* g, unsigned short* lds) {
    __builtin_amdgcn_global_load_lds(
        (const __attribute__((address_space(1))) u32*)g,
        (__attribute__((address_space(3))) u32*)lds, 16, 0, 0);
}

__device__ __forceinline__ void group_barrier(int* flags, int bg, int token) {
    __syncthreads();                      // drains vmcnt -> h stores at L3
    asm volatile("" ::: "memory");
    if (threadIdx.x == 0) {
        __hip_atomic_store(&flags[blockIdx.x], token, __ATOMIC_RELAXED, AGSCOPE);
    }
    if (threadIdx.x < 32) {
        while (__hip_atomic_load(&flags[bg + 8 * (int)threadIdx.x], __ATOMIC_RELAXED,
                                 AGSCOPE) < token) {
            __builtin_amdgcn_s_sleep(2);
        }
    }
    if (threadIdx.x == 0) {               // one buffer_inv per block per step
        (void)__hip_atomic_load(&flags[blockIdx.x], __ATOMIC_ACQUIRE, AGSCOPE);
    }
    __syncthreads();
    asm volatile("" ::: "memory");
}

__device__ __forceinline__ void emit_out(float hval,
                                         const float (*Wo)[256],
                                         float (*redsc)[8],
                                         float boV,
                                         float* __restrict__ op, int tid) {
    float p0 = Wo[0][tid] * hval;
    float p1 = Wo[1][tid] * hval;
    float p2 = Wo[2][tid] * hval;
    float p3 = Wo[3][tid] * hval;
    float p4 = Wo[4][tid] * hval;
    float p5 = Wo[5][tid] * hval;
    #pragma unroll
    for (int off = 1; off < 64; off <<= 1) {
        p0 += __shfl_xor(p0, off);
        p1 += __shfl_xor(p1, off);
        p2 += __shfl_xor(p2, off);
        p3 += __shfl_xor(p3, off);
        p4 += __shfl_xor(p4, off);
        p5 += __shfl_xor(p5, off);
    }
    const int wid = tid >> 6;
    if ((tid & 63) == 0) {
        redsc[wid][0] = p0; redsc[wid][1] = p1; redsc[wid][2] = p2;
        redsc[wid][3] = p3; redsc[wid][4] = p4; redsc[wid][5] = p5;
    }
    __syncthreads();
    if (tid < 6) {
        op[tid] = redsc[0][tid] + redsc[1][tid] + redsc[2][tid] + redsc[3][tid] + boV;
    }
}

__global__ __launch_bounds__(256, 1) void lstm_persist(
    const float* __restrict__ x,
    const float* __restrict__ W_ih1, const float* __restrict__ W_hh1,
    const float* __restrict__ b_ih1, const float* __restrict__ b_hh1,
    const float* __restrict__ W_ih2, const float* __restrict__ W_hh2,
    const float* __restrict__ b_ih2, const float* __restrict__ b_hh2,
    const float* __restrict__ W_out, const float* __restrict__ b_out,
    float* __restrict__ out,
    int* __restrict__ flags,
    unsigned short* __restrict__ B1h, unsigned short* __restrict__ B1l,
    unsigned short* __restrict__ B2h, unsigned short* __restrict__ B2l)
{
    __shared__ unsigned short sB1h[2][8][64][8];   // [half][chunk][lane][8] = 16KB, frag-linear
    __shared__ unsigned short sB1l[2][8][64][8];
    __shared__ unsigned short sB2h[2][8][64][8];
    __shared__ unsigned short sB2l[2][8][64][8];
    __shared__ float Wo[6][256];
    __shared__ float redsc[4][8];

    const int tid = threadIdx.x;
    const int bg  = blockIdx.x & 7;
    const int gg  = blockIdx.x >> 3;
    const int wid = tid >> 6;
    const int l   = tid & 63;
    const int gh  = wid >> 1;              // unit half of C tile
    const int bh  = wid & 1;               // batch half of C tile
    const int kl  = (l >> 4) << 3;         // lane k-offset within 32-chunk (A frags)
    // A-operand lane: row r32 = gh*16 + (l&15), row = ulocal*4 + gate (verified R6)
    const int r32  = (gh << 4) + (l & 15);
    const int gr_a = (r32 & 3) * HH + (gg << 3) + (r32 >> 2);
    // D-owner lane: unit du, batch db (verified R6)
    const int du       = (gh << 2) + (l >> 4);
    const int db       = (bh << 4) + (l & 15);
    const int unit_abs = (gg << 3) + du;
    const int db_abs   = (bg << 5) + db;
    const int ro       = (bg << 5) + gg;   // batch row whose `out` this WG emits

    // owner store swizzle: u16 offset inside a [bg] slab (8192 u16)
    const int so_base = bh * 4096 + (gg >> 2) * 512 + (gg & 3) * 128 + (l & 15) * 8 + du;
    // emit read swizzle: k = tid, b = gg (ro&31 == gg)
    const int eo = ((gg >> 4) * 4096) + ((tid >> 5) * 512) + (((tid >> 3) & 3) * 128)
                 + ((gg & 15) * 8) + (tid & 7);

    // ---- prologue: zero LDS frag arrays, load Wo ----
    for (int i = tid; i < 4096; i += 256) {
        ((u32*)sB1h)[i] = 0u; ((u32*)sB1l)[i] = 0u;
        ((u32*)sB2h)[i] = 0u; ((u32*)sB2l)[i] = 0u;
    }
    for (int i = tid; i < 6 * 256; i += 256) Wo[i >> 8][i & 255] = W_out[i];

    // ---- A-fragments: W rows -> bf16 hi/lo in VGPRs (one-time) ----
    s8v A1h[8], A1l[8], A2h[16], A2l[16];
    {
        const float* w1 = W_hh1 + gr_a * HH;
        #pragma unroll
        for (int c = 0; c < 8; ++c) pack8_hl(w1 + c * 32 + kl, A1h[c], A1l[c]);
        const float* w2i = W_ih2 + gr_a * HH;
        #pragma unroll
        for (int c = 0; c < 8; ++c) pack8_hl(w2i + c * 32 + kl, A2h[c], A2l[c]);
        const float* w2h = W_hh2 + gr_a * HH;
        #pragma unroll
        for (int c = 0; c < 8; ++c) pack8_hl(w2h + c * 32 + kl, A2h[8 + c], A2l[8 + c]);
    }

    // ---- D-owner constants ----
    float b1a[4], b2a[4], Wxr[4][6];
    #pragma unroll
    for (int g = 0; g < 4; ++g) {
        const int gr = g * HH + unit_abs;
        b1a[g] = b_ih1[gr] + b_hh1[gr];
        b2a[g] = b_ih2[gr] + b_hh2[gr];
        #pragma unroll
        for (int d = 0; d < 6; ++d) Wxr[g][d] = W_ih1[gr * DDIM + d];
    }
    const float boV = (tid < 6) ? b_out[tid] : 0.0f;
    float c1 = 0.0f, c2 = 0.0f;
    __syncthreads();

    #pragma unroll 1
    for (int t = 0; t < TT; ++t) {
        const int cur = t & 1, prv = cur ^ 1;

        // ---- P1: layer-1 MFMAs (B = h1(t-1), staged last step) ----
        const float* xp = x + (size_t)db_abs * (TT * DDIM) + t * DDIM;
        const f2v xA = *(const f2v*)(xp);
        const f2v xB = *(const f2v*)(xp + 2);
        const f2v xC = *(const f2v*)(xp + 4);

        f4v acc = {0.f, 0.f, 0.f, 0.f};
        #pragma unroll
        for (int c = 0; c < 8; ++c) {
            const s8v vhi = *(const s8v*)&sB1h[bh][c][l][0];
            const s8v vlo = *(const s8v*)&sB1l[bh][c][l][0];
            acc = MFMA(A1h[c], vhi, acc);
            acc = MFMA(A1h[c], vlo, acc);
            acc = MFMA(A1l[c], vhi, acc);
        }
        {
            float ga[4];
            #pragma unroll
            for (int g = 0; g < 4; ++g) {
                float a = acc[g] + b1a[g];
                a = fmaf(Wxr[g][0], xA.x, a); a = fmaf(Wxr[g][1], xA.y, a);
                a = fmaf(Wxr[g][2], xB.x, a); a = fmaf(Wxr[g][3], xB.y, a);
                a = fmaf(Wxr[g][4], xC.x, a); a = fmaf(Wxr[g][5], xC.y, a);
                ga[g] = a;
            }
            const float i1 = sigf(ga[0]), f1 = sigf(ga[1]);
            const float g1 = tanhf_fast(ga[2]), o1 = sigf(ga[3]);
            c1 = fmaf(f1, c1, i1 * g1);
            const float h1v = o1 * tanhf_fast(c1);
            unsigned short hh, hl;
            cvt_hl(h1v, hh, hl);
            const int i1x = (cur * 8 + bg) * 8192 + so_base;
            st_agent_u16(&B1h[i1x], hh);
            st_agent_u16(&B1l[i1x], hl);
        }

        // publish h1(t); h2(t-1) stores (last iter) publish too
        group_barrier(flags, bg, t + 1);

        // ---- emit loads FIRST (so their vmcnt wait doesn't drain the stage) ----
        unsigned short ehi = 0, elo = 0;
        if (t > 0) {
            const int eidx = (prv * 8 + bg) * 8192 + eo;
            ehi = B2h[eidx];
            elo = B2l[eidx];
        }

        // ---- stage h1(t) + h2(t-1) bf16 slabs into LDS (1 array per wave) ----
        {
            const unsigned short* gsrc;
            unsigned short* ldst;
            if (wid == 0)      { gsrc = B1h + (cur * 8 + bg) * 8192; ldst = &sB1h[0][0][0][0]; }
            else if (wid == 1) { gsrc = B1l + (cur * 8 + bg) * 8192; ldst = &sB1l[0][0][0][0]; }
            else if (wid == 2) { gsrc = B2h + (prv * 8 + bg) * 8192; ldst = &sB2h[0][0][0][0]; }
            else               { gsrc = B2l + (prv * 8 + bg) * 8192; ldst = &sB2l[0][0][0][0]; }
            #pragma unroll
            for (int i = 0; i < 16; ++i) {
                stage16(gsrc + i * 512 + l * 8, ldst + i * 512);
            }
        }

        // ---- emit out(t-1) (covers stage latency) ----
        if (t > 0) {
            const float hval = __uint_as_float((u32)ehi << 16) + __uint_as_float((u32)elo << 16);
            emit_out(hval, Wo, redsc, boV, out + ro * (TT * DDIM) + (t - 1) * DDIM, tid);
        }
        __syncthreads();   // stage complete (vmcnt drained) + redsc settled

        // ---- P5: layer-2 MFMAs (B = [h1(t); h2(t-1)] from LDS) ----
        f4v acc2 = {0.f, 0.f, 0.f, 0.f};
        #pragma unroll
        for (int c = 0; c < 8; ++c) {
            const s8v vhi = *(const s8v*)&sB1h[bh][c][l][0];
            const s8v vlo = *(const s8v*)&sB1l[bh][c][l][0];
            acc2 = MFMA(A2h[c], vhi, acc2);
            acc2 = MFMA(A2h[c], vlo, acc2);
            acc2 = MFMA(A2l[c], vhi, acc2);
        }
        #pragma unroll
        for (int c = 0; c < 8; ++c) {
            const s8v vhi = *(const s8v*)&sB2h[bh][c][l][0];
            const s8v vlo = *(const s8v*)&sB2l[bh][c][l][0];
            acc2 = MFMA(A2h[8 + c], vhi, acc2);
            acc2 = MFMA(A2h[8 + c], vlo, acc2);
            acc2 = MFMA(A2l[8 + c], vhi, acc2);
        }
        {
            const float i2  = sigf(acc2[0] + b2a[0]);
            const float f2g = sigf(acc2[1] + b2a[1]);
            const float g2  = tanhf_fast(acc2[2] + b2a[2]);
            const float o2  = sigf(acc2[3] + b2a[3]);
            c2 = fmaf(f2g, c2, i2 * g2);
            const float h2v = o2 * tanhf_fast(c2);
            unsigned short hh, hl;
            cvt_hl(h2v, hh, hl);
            const int i2x = (cur * 8 + bg) * 8192 + so_base;
            st_agent_u16(&B2h[i2x], hh);
            st_agent_u16(&B2l[i2x], hl);
        }
    }

    group_barrier(flags, bg, TT + 1);
    {
        const int prvF = (TT - 1) & 1;
        const int eidx = (prvF * 8 + bg) * 8192 + eo;
        const float hval = __uint_as_float((u32)B2h[eidx] << 16)
                         + __uint_as_float((u32)B2l[eidx] << 16);
        emit_out(hval, Wo, redsc, boV, out + ro * (TT * DDIM) + (TT - 1) * DDIM, tid);
    }
}

extern "C" void kernel_launch(void* const* d_in, const int* in_sizes, int n_in,
                              void* d_out, int out_size, void* d_ws, size_t ws_size,
                              hipStream_t stream) {
    (void)in_sizes; (void)n_in; (void)out_size; (void)ws_size;
    const float* x     = (const float*)d_in[0];
    const float* W_ih1 = (const float*)d_in[1];
    const float* W_hh1 = (const float*)d_in[2];
    const float* b_ih1 = (const float*)d_in[3];
    const float* b_hh1 = (const float*)d_in[4];
    const float* W_ih2 = (const float*)d_in[5];
    const float* W_hh2 = (const float*)d_in[6];
    const float* b_ih2 = (const float*)d_in[7];
    const float* b_hh2 = (const float*)d_in[8];
    const float* W_out = (const float*)d_in[9];
    const float* b_out = (const float*)d_in[10];
    float* out = (float*)d_out;

    char* ws = (char*)d_ws;
    int* flags = (int*)ws;                              // 1 KB
    unsigned short* B1h = (unsigned short*)(ws + 1024);           // 256 KB each:
    unsigned short* B1l = (unsigned short*)(ws + 1024 + 262144);  // [2][8][8192 u16]
    unsigned short* B2h = (unsigned short*)(ws + 1024 + 524288);
    unsigned short* B2l = (unsigned short*)(ws + 1024 + 786432);

    hipMemsetAsync(d_ws, 0, 1049600, stream);

    hipLaunchKernelGGL(lstm_persist, dim3(256), dim3(256), 0, stream,
                       x, W_ih1, W_hh1, b_ih1, b_hh1,
                       W_ih2, W_hh2, b_ih2, b_hh2,
                       W_out, b_out, out, flags, B1h, B1l, B2h, B2l);
}

// Round 8
// 6287.213 us; speedup vs baseline: 4.1884x; 1.2118x over previous
//
#include <hip/hip_runtime.h>

#define BB 256
#define TT 1024
#define DDIM 6
#define HH 256
#define AGSCOPE __HIP_MEMORY_SCOPE_AGENT

typedef float  f4v __attribute__((ext_vector_type(4)));
typedef float  f2v __attribute__((ext_vector_type(2)));
typedef short  s8v __attribute__((ext_vector_type(8)));
typedef unsigned int u32;

// grid: 256 blocks = 8 batch-groups (bg = blk&7, 32 batches) x 32 unit-groups (gg = blk>>3, 8 units)
// block: 4 waves; wave (gh,bh): C rows 16gh..+15 (row = ulocal*4+gate) x batches 16bh..+15.
// A (weights) bf16 hi/lo frags in VGPRs (converted once). B (h) bf16 hi/lo in LDS, FRAG-LINEAR:
// [half][chunk][lane][8] -> ds_read_b128 is a linear 1KB wave block (0 conflicts, verified R7),
// global->LDS staging is an identity copy via global_load_lds_dwordx4.
// Coherence (R8): ALL cross-WG stores are write-through agent (sc0 sc1) -> L3 always fresh;
// ALL cross-WG reads bypass caches (poll: agent atomics; stage: aux=17 = sc0|sc1) -> NO
// buffer_inv anywhere (R7 ran 32 invs/XCD/step, thrashing L2 for x/slabs). L1/L2 now retain
// read-only inputs across steps. emit reads the staged LDS slab (no global emit loads).

__device__ __forceinline__ float sigf(float x) {
    return __builtin_amdgcn_rcpf(1.0f + __expf(-x));
}
__device__ __forceinline__ float tanhf_fast(float x) {
    return fmaf(2.0f, __builtin_amdgcn_rcpf(1.0f + __expf(-2.0f * x)), -1.0f);
}
__device__ __forceinline__ void st_agent_u16(unsigned short* p, unsigned short v) {
    __hip_atomic_store(p, v, __ATOMIC_RELAXED, AGSCOPE);
}

#define MFMA(a, b, c) __builtin_amdgcn_mfma_f32_16x16x32_bf16(a, b, c, 0, 0, 0)

// f32 -> bf16 hi (RNE) + bf16 lo (RNE of residual)
__device__ __forceinline__ void cvt_hl(float v, unsigned short& hi, unsigned short& lo) {
    u32 u = __float_as_uint(v);
    u32 r = (u + 0x7fffu + ((u >> 16) & 1u)) & 0xffff0000u;
    hi = (unsigned short)(r >> 16);
    float lof = v - __uint_as_float(r);
    u32 u2 = __float_as_uint(lof);
    lo = (unsigned short)((u2 + 0x7fffu + ((u2 >> 16) & 1u)) >> 16);
}

__device__ __forceinline__ void pack8_hl(const float* __restrict__ p, s8v& hi, s8v& lo) {
    #pragma unroll
    for (int j = 0; j < 8; ++j) {
        unsigned short h, l;
        cvt_hl(p[j], h, l);
        hi[j] = (short)h;
        lo[j] = (short)l;
    }
}

// async 16B/lane global->LDS copy; aux=17 = sc0|sc1: read at system-coherent point (L3),
// bypassing (possibly stale) L1/L2 clean lines -> no invalidate needed.
__device__ __forceinline__ void stage16(const unsigned short* g, unsigned short* lds) {
    __builtin_amdgcn_global_load_lds(
        (const __attribute__((address_space(1))) u32*)g,
        (__attribute__((address_space(3))) u32*)lds, 16, 0, 17);
}

__device__ __forceinline__ void group_barrier(int* flags, int bg, int token) {
    __syncthreads();                      // drains vmcnt -> h stores at L3
    asm volatile("" ::: "memory");
    if (threadIdx.x == 0) {
        __hip_atomic_store(&flags[blockIdx.x], token, __ATOMIC_RELAXED, AGSCOPE);
    }
    if (threadIdx.x < 32) {
        while (__hip_atomic_load(&flags[bg + 8 * (int)threadIdx.x], __ATOMIC_RELAXED,
                                 AGSCOPE) < token) {
            __builtin_amdgcn_s_sleep(1);
        }
    }
    __syncthreads();
    asm volatile("" ::: "memory");
}

__device__ __forceinline__ void emit_out(float hval,
                                         const float (*Wo)[256],
                                         float (*redsc)[8],
                                         float boV,
                                         float* __restrict__ op, int tid) {
    float p0 = Wo[0][tid] * hval;
    float p1 = Wo[1][tid] * hval;
    float p2 = Wo[2][tid] * hval;
    float p3 = Wo[3][tid] * hval;
    float p4 = Wo[4][tid] * hval;
    float p5 = Wo[5][tid] * hval;
    #pragma unroll
    for (int off = 1; off < 64; off <<= 1) {
        p0 += __shfl_xor(p0, off);
        p1 += __shfl_xor(p1, off);
        p2 += __shfl_xor(p2, off);
        p3 += __shfl_xor(p3, off);
        p4 += __shfl_xor(p4, off);
        p5 += __shfl_xor(p5, off);
    }
    const int wid = tid >> 6;
    if ((tid & 63) == 0) {
        redsc[wid][0] = p0; redsc[wid][1] = p1; redsc[wid][2] = p2;
        redsc[wid][3] = p3; redsc[wid][4] = p4; redsc[wid][5] = p5;
    }
    __syncthreads();
    if (tid < 6) {
        op[tid] = redsc[0][tid] + redsc[1][tid] + redsc[2][tid] + redsc[3][tid] + boV;
    }
}

__global__ __launch_bounds__(256, 1) void lstm_persist(
    const float* __restrict__ x,
    const float* __restrict__ W_ih1, const float* __restrict__ W_hh1,
    const float* __restrict__ b_ih1, const float* __restrict__ b_hh1,
    const float* __restrict__ W_ih2, const float* __restrict__ W_hh2,
    const float* __restrict__ b_ih2, const float* __restrict__ b_hh2,
    const float* __restrict__ W_out, const float* __restrict__ b_out,
    float* __restrict__ out,
    int* __restrict__ flags,
    unsigned short* __restrict__ B1h, unsigned short* __restrict__ B1l,
    unsigned short* __restrict__ B2h, unsigned short* __restrict__ B2l)
{
    __shared__ unsigned short sB1h[2][8][64][8];   // [half][chunk][lane][8] = 16KB, frag-linear
    __shared__ unsigned short sB1l[2][8][64][8];
    __shared__ unsigned short sB2h[2][8][64][8];
    __shared__ unsigned short sB2l[2][8][64][8];
    __shared__ float Wo[6][256];
    __shared__ float redsc[4][8];

    const int tid = threadIdx.x;
    const int bg  = blockIdx.x & 7;
    const int gg  = blockIdx.x >> 3;
    const int wid = tid >> 6;
    const int l   = tid & 63;
    const int gh  = wid >> 1;              // unit half of C tile
    const int bh  = wid & 1;               // batch half of C tile
    const int kl  = (l >> 4) << 3;         // lane k-offset within 32-chunk (A frags)
    // A-operand lane: row r32 = gh*16 + (l&15), row = ulocal*4 + gate (verified R6/R7)
    const int r32  = (gh << 4) + (l & 15);
    const int gr_a = (r32 & 3) * HH + (gg << 3) + (r32 >> 2);
    // D-owner lane: unit du, batch db (verified R6/R7)
    const int du       = (gh << 2) + (l >> 4);
    const int db       = (bh << 4) + (l & 15);
    const int unit_abs = (gg << 3) + du;
    const int db_abs   = (bg << 5) + db;
    const int ro       = (bg << 5) + gg;   // batch row whose `out` this WG emits

    // owner store swizzle: u16 offset inside a [bg] slab (8192 u16)
    const int so_base = bh * 4096 + (gg >> 2) * 512 + (gg & 3) * 128 + (l & 15) * 8 + du;
    // emit read: identity-copy LDS flat offset for (b=gg, k=tid)
    const int eo = ((gg >> 4) * 4096) + ((tid >> 5) * 512) + (((tid >> 3) & 3) * 128)
                 + ((gg & 15) * 8) + (tid & 7);

    // ---- prologue: zero LDS frag arrays (h(0)=0), load Wo ----
    for (int i = tid; i < 4096; i += 256) {
        ((u32*)sB1h)[i] = 0u; ((u32*)sB1l)[i] = 0u;
        ((u32*)sB2h)[i] = 0u; ((u32*)sB2l)[i] = 0u;
    }
    for (int i = tid; i < 6 * 256; i += 256) Wo[i >> 8][i & 255] = W_out[i];

    // ---- A-fragments: W rows -> bf16 hi/lo in VGPRs (one-time) ----
    s8v A1h[8], A1l[8], A2h[16], A2l[16];
    {
        const float* w1 = W_hh1 + gr_a * HH;
        #pragma unroll
        for (int c = 0; c < 8; ++c) pack8_hl(w1 + c * 32 + kl, A1h[c], A1l[c]);
        const float* w2i = W_ih2 + gr_a * HH;
        #pragma unroll
        for (int c = 0; c < 8; ++c) pack8_hl(w2i + c * 32 + kl, A2h[c], A2l[c]);
        const float* w2h = W_hh2 + gr_a * HH;
        #pragma unroll
        for (int c = 0; c < 8; ++c) pack8_hl(w2h + c * 32 + kl, A2h[8 + c], A2l[8 + c]);
    }

    // ---- D-owner constants ----
    float b1a[4], b2a[4], Wxr[4][6];
    #pragma unroll
    for (int g = 0; g < 4; ++g) {
        const int gr = g * HH + unit_abs;
        b1a[g] = b_ih1[gr] + b_hh1[gr];
        b2a[g] = b_ih2[gr] + b_hh2[gr];
        #pragma unroll
        for (int d = 0; d < 6; ++d) Wxr[g][d] = W_ih1[gr * DDIM + d];
    }
    const float boV = (tid < 6) ? b_out[tid] : 0.0f;
    float c1 = 0.0f, c2 = 0.0f;

    // x(0) prefetch
    const float* xbase = x + (size_t)db_abs * (TT * DDIM);
    f2v xA = *(const f2v*)(xbase);
    f2v xB = *(const f2v*)(xbase + 2);
    f2v xC = *(const f2v*)(xbase + 4);
    __syncthreads();

    #pragma unroll 1
    for (int t = 0; t < TT; ++t) {
        const int cur = t & 1, prv = cur ^ 1;

        // ---- P1: layer-1 MFMAs (B = h1(t-1), staged last step), 3 indep chains ----
        f4v aA = {0.f,0.f,0.f,0.f}, aB = {0.f,0.f,0.f,0.f}, aC = {0.f,0.f,0.f,0.f};
        #pragma unroll
        for (int c = 0; c < 8; ++c) {
            const s8v vhi = *(const s8v*)&sB1h[bh][c][l][0];
            const s8v vlo = *(const s8v*)&sB1l[bh][c][l][0];
            aA = MFMA(A1h[c], vhi, aA);
            aB = MFMA(A1h[c], vlo, aB);
            aC = MFMA(A1l[c], vhi, aC);
        }
        {
            const f4v acc = (aA + aB) + aC;
            float ga[4];
            #pragma unroll
            for (int g = 0; g < 4; ++g) {
                float a = acc[g] + b1a[g];
                a = fmaf(Wxr[g][0], xA.x, a); a = fmaf(Wxr[g][1], xA.y, a);
                a = fmaf(Wxr[g][2], xB.x, a); a = fmaf(Wxr[g][3], xB.y, a);
                a = fmaf(Wxr[g][4], xC.x, a); a = fmaf(Wxr[g][5], xC.y, a);
                ga[g] = a;
            }
            const float i1 = sigf(ga[0]), f1 = sigf(ga[1]);
            const float g1 = tanhf_fast(ga[2]), o1 = sigf(ga[3]);
            c1 = fmaf(f1, c1, i1 * g1);
            const float h1v = o1 * tanhf_fast(c1);
            unsigned short hh, hl;
            cvt_hl(h1v, hh, hl);
            const int i1x = (cur * 8 + bg) * 8192 + so_base;
            st_agent_u16(&B1h[i1x], hh);
            st_agent_u16(&B1l[i1x], hl);
        }

        // publish h1(t); h2(t-1) stores (last iter) publish too
        group_barrier(flags, bg, t + 1);

        // ---- stage h1(t) (+ h2(t-1) when t>0) into LDS; 1 array per wave ----
        if (wid == 0) {
            const unsigned short* g = B1h + (cur * 8 + bg) * 8192;
            #pragma unroll
            for (int i = 0; i < 16; ++i) stage16(g + i * 512 + l * 8, &sB1h[0][0][0][0] + i * 512);
        } else if (wid == 1) {
            const unsigned short* g = B1l + (cur * 8 + bg) * 8192;
            #pragma unroll
            for (int i = 0; i < 16; ++i) stage16(g + i * 512 + l * 8, &sB1l[0][0][0][0] + i * 512);
        } else if (wid == 2) {
            if (t > 0) {
                const unsigned short* g = B2h + (prv * 8 + bg) * 8192;
                #pragma unroll
                for (int i = 0; i < 16; ++i) stage16(g + i * 512 + l * 8, &sB2h[0][0][0][0] + i * 512);
            }
        } else {
            if (t > 0) {
                const unsigned short* g = B2l + (prv * 8 + bg) * 8192;
                #pragma unroll
                for (int i = 0; i < 16; ++i) stage16(g + i * 512 + l * 8, &sB2l[0][0][0][0] + i * 512);
            }
        }

        // x(t+1) register prefetch (overlaps stage latency)
        const float* xnp = xbase + ((t + 1 < TT) ? (t + 1) : t) * DDIM;
        const f2v xAn = *(const f2v*)(xnp);
        const f2v xBn = *(const f2v*)(xnp + 2);
        const f2v xCn = *(const f2v*)(xnp + 4);

        __syncthreads();   // stage complete (vmcnt drained per wave)

        // ---- emit out(t-1) from the staged LDS slab ----
        if (t > 0) {
            const float hval =
                __uint_as_float((u32)(((const unsigned short*)sB2h)[eo]) << 16)
              + __uint_as_float((u32)(((const unsigned short*)sB2l)[eo]) << 16);
            emit_out(hval, Wo, redsc, boV, out + ro * (TT * DDIM) + (t - 1) * DDIM, tid);
        }

        // ---- P5: layer-2 MFMAs (B = [h1(t); h2(t-1)] from LDS), 3 indep chains ----
        f4v eA = {0.f,0.f,0.f,0.f}, eB = {0.f,0.f,0.f,0.f}, eC = {0.f,0.f,0.f,0.f};
        #pragma unroll
        for (int c = 0; c < 8; ++c) {
            const s8v vhi = *(const s8v*)&sB1h[bh][c][l][0];
            const s8v vlo = *(const s8v*)&sB1l[bh][c][l][0];
            eA = MFMA(A2h[c], vhi, eA);
            eB = MFMA(A2h[c], vlo, eB);
            eC = MFMA(A2l[c], vhi, eC);
        }
        #pragma unroll
        for (int c = 0; c < 8; ++c) {
            const s8v vhi = *(const s8v*)&sB2h[bh][c][l][0];
            const s8v vlo = *(const s8v*)&sB2l[bh][c][l][0];
            eA = MFMA(A2h[8 + c], vhi, eA);
            eB = MFMA(A2h[8 + c], vlo, eB);
            eC = MFMA(A2l[8 + c], vhi, eC);
        }
        {
            const f4v acc2 = (eA + eB) + eC;
            const float i2  = sigf(acc2[0] + b2a[0]);
            const float f2g = sigf(acc2[1] + b2a[1]);
            const float g2  = tanhf_fast(acc2[2] + b2a[2]);
            const float o2  = sigf(acc2[3] + b2a[3]);
            c2 = fmaf(f2g, c2, i2 * g2);
            const float h2v = o2 * tanhf_fast(c2);
            unsigned short hh, hl;
            cvt_hl(h2v, hh, hl);
            const int i2x = (cur * 8 + bg) * 8192 + so_base;
            st_agent_u16(&B2h[i2x], hh);
            st_agent_u16(&B2l[i2x], hl);
        }

        xA = xAn; xB = xBn; xC = xCn;
    }

    // final: publish h2(TT-1), stage it, emit from LDS
    group_barrier(flags, bg, TT + 1);
    {
        const int curF = (TT - 1) & 1;
        if (wid == 2) {
            const unsigned short* g = B2h + (curF * 8 + bg) * 8192;
            #pragma unroll
            for (int i = 0; i < 16; ++i) stage16(g + i * 512 + l * 8, &sB2h[0][0][0][0] + i * 512);
        } else if (wid == 3) {
            const unsigned short* g = B2l + (curF * 8 + bg) * 8192;
            #pragma unroll
            for (int i = 0; i < 16; ++i) stage16(g + i * 512 + l * 8, &sB2l[0][0][0][0] + i * 512);
        }
        __syncthreads();
        const float hval =
            __uint_as_float((u32)(((const unsigned short*)sB2h)[eo]) << 16)
          + __uint_as_float((u32)(((const unsigned short*)sB2l)[eo]) << 16);
        emit_out(hval, Wo, redsc, boV, out + ro * (TT * DDIM) + (TT - 1) * DDIM, tid);
    }
}

extern "C" void kernel_launch(void* const* d_in, const int* in_sizes, int n_in,
                              void* d_out, int out_size, void* d_ws, size_t ws_size,
                              hipStream_t stream) {
    (void)in_sizes; (void)n_in; (void)out_size; (void)ws_size;
    const float* x     = (const float*)d_in[0];
    const float* W_ih1 = (const float*)d_in[1];
    const float* W_hh1 = (const float*)d_in[2];
    const float* b_ih1 = (const float*)d_in[3];
    const float* b_hh1 = (const float*)d_in[4];
    const float* W_ih2 = (const float*)d_in[5];
    const float* W_hh2 = (const float*)d_in[6];
    const float* b_ih2 = (const float*)d_in[7];
    const float* b_hh2 = (const float*)d_in[8];
    const float* W_out = (const float*)d_in[9];
    const float* b_out = (const float*)d_in[10];
    float* out = (float*)d_out;

    char* ws = (char*)d_ws;
    int* flags = (int*)ws;                              // 1 KB
    unsigned short* B1h = (unsigned short*)(ws + 1024);           // 256 KB each:
    unsigned short* B1l = (unsigned short*)(ws + 1024 + 262144);  // [2][8][8192 u16]
    unsigned short* B2h = (unsigned short*)(ws + 1024 + 524288);
    unsigned short* B2l = (unsigned short*)(ws + 1024 + 786432);

    // only the flag array needs zeroing (B slabs are fully written before any read:
    // B1 staged same-step it's stored; B2 staging skipped at t=0)
    hipMemsetAsync(d_ws, 0, 1024, stream);

    hipLaunchKernelGGL(lstm_persist, dim3(256), dim3(256), 0, stream,
                       x, W_ih1, W_hh1, b_ih1, b_hh1,
                       W_ih2, W_hh2, b_ih2, b_hh2,
                       W_out, b_out, out, flags, B1h, B1l, B2h, B2l);
}

// Round 10
// 5172.302 us; speedup vs baseline: 5.0913x; 1.2156x over previous
//
#include <hip/hip_runtime.h>

#define TT 1024
#define DDIM 6
#define HH 256
#define AGSCOPE __HIP_MEMORY_SCOPE_AGENT
#define LOSC 4.8828125e-4f   // 2^-11: lo-plane descale

typedef float    f4v __attribute__((ext_vector_type(4)));
typedef float    f2v __attribute__((ext_vector_type(2)));
typedef _Float16 hf;
typedef hf       h8v __attribute__((ext_vector_type(8)));
typedef unsigned int u32;

// grid: 512 blocks = 16 batch-groups (bg = blk>>5, 16 batches) x 32 unit-groups (gg = blk&31).
// 2 blocks/CU (blk, blk+256 -> bg differs by 8): anti-phased barrier domains share SIMDs.
// block: 4 waves (gh: unit-half, kh: K-half); K-split partials reduced via pscr in LDS.
// Precision (R10): fp16 hi + 2^11-scaled fp16 lo split of W and h (captures ~2^-23 vs bf16's
// 2^-17 -> recurrence noise floor ~64x lower; R9's failure was chaotic amplification of the
// bf16 exchange quantization). gates = accHH + 2^-11*(accHL + accLH).
// Slabs/stage/barrier protocol unchanged from R7-R9 (frag-linear identity copy, aux=17 stage,
// write-through agent stores, flag barrier, no invalidates). D/A lane maps verified R6-R8.

__device__ __forceinline__ float sigf(float x) {
    return __builtin_amdgcn_rcpf(1.0f + __expf(-x));
}
__device__ __forceinline__ float tanhf_fast(float x) {
    return fmaf(2.0f, __builtin_amdgcn_rcpf(1.0f + __expf(-2.0f * x)), -1.0f);
}
__device__ __forceinline__ void st_agent_u16(unsigned short* p, unsigned short v) {
    __hip_atomic_store(p, v, __ATOMIC_RELAXED, AGSCOPE);
}

#define MFMA(a, b, c) __builtin_amdgcn_mfma_f32_16x16x32_f16(a, b, c, 0, 0, 0)

// f32 -> fp16 hi (RNE) + fp16 lo scaled by 2^11 (keeps lo in normal range)
__device__ __forceinline__ void cvt_hl(float v, hf& hi, hf& lo) {
    hi = (hf)v;
    lo = (hf)((v - (float)hi) * 2048.0f);
}
__device__ __forceinline__ void pack8_hl(const float* __restrict__ p, h8v& hi, h8v& lo) {
    #pragma unroll
    for (int j = 0; j < 8; ++j) {
        hf h, l;
        cvt_hl(p[j], h, l);
        hi[j] = h;
        lo[j] = l;
    }
}

// async 16B/lane global->LDS copy; aux=17 = sc0|sc1 (read at L3 coherence point)
__device__ __forceinline__ void stage16(const unsigned short* g, unsigned short* lds) {
    __builtin_amdgcn_global_load_lds(
        (const __attribute__((address_space(1))) u32*)g,
        (__attribute__((address_space(3))) u32*)lds, 16, 0, 17);
}

__device__ __forceinline__ void group_barrier(int* flags, int bg, int token) {
    __syncthreads();                      // drains vmcnt -> h stores at L3
    asm volatile("" ::: "memory");
    if (threadIdx.x == 0) {
        __hip_atomic_store(&flags[blockIdx.x], token, __ATOMIC_RELAXED, AGSCOPE);
    }
    if (threadIdx.x < 32) {               // 32 peers share bg
        while (__hip_atomic_load(&flags[(bg << 5) + (int)threadIdx.x], __ATOMIC_RELAXED,
                                 AGSCOPE) < token) {
            __builtin_amdgcn_s_sleep(1);
        }
    }
    __syncthreads();
    asm volatile("" ::: "memory");
}

__device__ __forceinline__ void emit_out(float hval,
                                         const float (*Wo)[256],
                                         float (*redsc)[8],
                                         float boV,
                                         float* __restrict__ op, int tid) {
    float p0 = Wo[0][tid] * hval;
    float p1 = Wo[1][tid] * hval;
    float p2 = Wo[2][tid] * hval;
    float p3 = Wo[3][tid] * hval;
    float p4 = Wo[4][tid] * hval;
    float p5 = Wo[5][tid] * hval;
    #pragma unroll
    for (int off = 1; off < 64; off <<= 1) {
        p0 += __shfl_xor(p0, off);
        p1 += __shfl_xor(p1, off);
        p2 += __shfl_xor(p2, off);
        p3 += __shfl_xor(p3, off);
        p4 += __shfl_xor(p4, off);
        p5 += __shfl_xor(p5, off);
    }
    const int wid = tid >> 6;
    if ((tid & 63) == 0) {
        redsc[wid][0] = p0; redsc[wid][1] = p1; redsc[wid][2] = p2;
        redsc[wid][3] = p3; redsc[wid][4] = p4; redsc[wid][5] = p5;
    }
    __syncthreads();
    if (tid < 6) {
        op[tid] = redsc[0][tid] + redsc[1][tid] + redsc[2][tid] + redsc[3][tid] + boV;
    }
}

__global__ __launch_bounds__(256, 2) void lstm_persist(
    const float* __restrict__ x,
    const float* __restrict__ W_ih1, const float* __restrict__ W_hh1,
    const float* __restrict__ b_ih1, const float* __restrict__ b_hh1,
    const float* __restrict__ W_ih2, const float* __restrict__ W_hh2,
    const float* __restrict__ b_ih2, const float* __restrict__ b_hh2,
    const float* __restrict__ W_out, const float* __restrict__ b_out,
    float* __restrict__ out,
    int* __restrict__ flags,
    unsigned short* __restrict__ B1h, unsigned short* __restrict__ B1l,
    unsigned short* __restrict__ B2h, unsigned short* __restrict__ B2l)
{
    __shared__ unsigned short sB1h[8][64][8], sB1l[8][64][8];   // 8KB each, frag-linear
    __shared__ unsigned short sB2h[8][64][8], sB2l[8][64][8];
    __shared__ hf    sA2l[4][8][64][8];          // layer-2 A lo-plane frags, per-wave linear (32KB)
    __shared__ float sWx[4][8][8];               // x-weights [gate][du][d]
    __shared__ float Wo[6][256];
    __shared__ float redsc[4][8];
    __shared__ f4v pscrA[2][64], pscrB[2][64];   // K-half partial sums (P1 / P5)

    const int tid = threadIdx.x;
    const int blk = blockIdx.x;
    const int gg  = blk & 31;              // unit-group (8 units)
    const int bg  = blk >> 5;              // batch-group (16 batches)
    const int wid = tid >> 6;
    const int l   = tid & 63;
    const int gh  = wid >> 1;              // unit half (tile)
    const int kh  = wid & 1;               // K half / layer-2 matrix select
    const int kl  = (l >> 4) << 3;         // lane k-offset within 32-chunk
    // A-operand lane (R6-verified): row r32 within 32 gate-rows; row = du*4 + gate
    const int r32  = (gh << 4) + (l & 15);
    const int gr_a = (r32 & 3) * HH + (gg << 3) + (r32 >> 2);
    // D-owner lane (kh==0 waves): unit du, batch db
    const int du       = (gh << 2) + (l >> 4);
    const int db       = l & 15;
    const int unit_abs = (gg << 3) + du;
    const int db_abs   = (bg << 4) + db;
    const int ro       = (bg << 4) + (gg & 15);   // emitted batch row (gg<16 WGs only)

    // owner store u16 offset inside a slab: (u>>5)*512 + ((u>>3)&3)*128 + b*8 + (u&7)
    const int so_base = (unit_abs >> 5) * 512 + ((unit_abs >> 3) & 3) * 128
                      + db * 8 + (unit_abs & 7);
    // emit read (LDS, identity copy): b_local = gg&15, u = tid
    const int eo = (tid >> 5) * 512 + (((tid >> 3) & 3) * 128) + (gg & 15) * 8 + (tid & 7);

    // ---- prologue: zero slabs (h(0)=0), load Wo, x-weights ----
    for (int i = tid; i < 2048; i += 256) {
        ((u32*)sB1h)[i] = 0u; ((u32*)sB1l)[i] = 0u;
        ((u32*)sB2h)[i] = 0u; ((u32*)sB2l)[i] = 0u;
    }
    for (int i = tid; i < 6 * 256; i += 256) Wo[i >> 8][i & 255] = W_out[i];
    for (int i = tid; i < 192; i += 256) {
        const int r = i / 6, d = i - r * 6;          // r = gate*8 + du_
        sWx[r >> 3][r & 7][d] = W_ih1[((r >> 3) * HH + (gg << 3) + (r & 7)) * DDIM + d];
    }

    // ---- A-fragments: hi planes in VGPR; layer-2 lo planes in LDS (per-wave, own-lane) ----
    h8v A1h[4], A1l[4], A2h[8];
    #pragma unroll
    for (int c = 0; c < 4; ++c) {
        const int cc = (kh << 2) + c;
        pack8_hl(W_hh1 + gr_a * HH + cc * 32 + kl, A1h[c], A1l[c]);
    }
    {
        const float* W2 = kh ? W_hh2 : W_ih2;    // kh0: h1(t) input, kh1: h2(t-1) input
        #pragma unroll
        for (int c = 0; c < 8; ++c) {
            h8v hi, lo;
            pack8_hl(W2 + gr_a * HH + c * 32 + kl, hi, lo);
            A2h[c] = hi;
            *(h8v*)&sA2l[wid][c][l][0] = lo;     // own-lane write, read back by same lane
        }
    }

    // ---- D-owner constants ----
    float b1a[4], b2a[4];
    #pragma unroll
    for (int g = 0; g < 4; ++g) {
        const int gr = g * HH + unit_abs;
        b1a[g] = b_ih1[gr] + b_hh1[gr];
        b2a[g] = b_ih2[gr] + b_hh2[gr];
    }
    const float boV = (tid < 6) ? b_out[tid] : 0.0f;
    float c1 = 0.0f, c2 = 0.0f;

    const float* xbase = x + (size_t)db_abs * (TT * DDIM);
    f2v xA = {0.f,0.f}, xB = {0.f,0.f}, xC = {0.f,0.f};
    if (kh == 0) {
        xA = *(const f2v*)(xbase);
        xB = *(const f2v*)(xbase + 2);
        xC = *(const f2v*)(xbase + 4);
    }
    __syncthreads();

    #pragma unroll 1
    for (int t = 0; t < TT; ++t) {
        const int cur = t & 1, prv = cur ^ 1;

        // ---- P1: layer-1 (this wave's K-half), 3 chains: HH, H*lo', lo'*H ----
        f4v aA = {0.f,0.f,0.f,0.f}, aB = {0.f,0.f,0.f,0.f}, aC = {0.f,0.f,0.f,0.f};
        #pragma unroll
        for (int c = 0; c < 4; ++c) {
            const int cc = (kh << 2) + c;
            const h8v vhi = *(const h8v*)&sB1h[cc][l][0];
            const h8v vlo = *(const h8v*)&sB1l[cc][l][0];
            aA = MFMA(A1h[c], vhi, aA);
            aB = MFMA(A1h[c], vlo, aB);
            aC = MFMA(A1l[c], vhi, aC);
        }
        {
            const f4v p1 = aA + (aB + aC) * LOSC;
            if (kh) pscrA[gh][l] = p1;
            __syncthreads();
            if (!kh) {
                const f4v acc = p1 + pscrA[gh][l];
                float ga[4];
                #pragma unroll
                for (int g = 0; g < 4; ++g) {
                    float a = acc[g] + b1a[g];
                    a = fmaf(sWx[g][du][0], xA.x, a); a = fmaf(sWx[g][du][1], xA.y, a);
                    a = fmaf(sWx[g][du][2], xB.x, a); a = fmaf(sWx[g][du][3], xB.y, a);
                    a = fmaf(sWx[g][du][4], xC.x, a); a = fmaf(sWx[g][du][5], xC.y, a);
                    ga[g] = a;
                }
                const float i1 = sigf(ga[0]), f1 = sigf(ga[1]);
                const float g1 = tanhf_fast(ga[2]), o1 = sigf(ga[3]);
                c1 = fmaf(f1, c1, i1 * g1);
                const float h1v = o1 * tanhf_fast(c1);
                hf hh, hl;
                cvt_hl(h1v, hh, hl);
                const int idx = (cur * 16 + bg) * 4096 + so_base;
                st_agent_u16(&B1h[idx], __builtin_bit_cast(unsigned short, hh));
                st_agent_u16(&B1l[idx], __builtin_bit_cast(unsigned short, hl));
            }
        }

        // publish h1(t) (+ h2(t-1) stored last step)
        group_barrier(flags, bg, t + 1);

        // ---- stage slabs (1 array per wave, 8 insts each) ----
        if (wid == 0) {
            const unsigned short* g = B1h + (cur * 16 + bg) * 4096;
            #pragma unroll
            for (int i = 0; i < 8; ++i) stage16(g + i * 512 + l * 8, &sB1h[0][0][0] + i * 512);
        } else if (wid == 1) {
            const unsigned short* g = B1l + (cur * 16 + bg) * 4096;
            #pragma unroll
            for (int i = 0; i < 8; ++i) stage16(g + i * 512 + l * 8, &sB1l[0][0][0] + i * 512);
        } else if (wid == 2) {
            if (t > 0) {
                const unsigned short* g = B2h + (prv * 16 + bg) * 4096;
                #pragma unroll
                for (int i = 0; i < 8; ++i) stage16(g + i * 512 + l * 8, &sB2h[0][0][0] + i * 512);
            }
        } else {
            if (t > 0) {
                const unsigned short* g = B2l + (prv * 16 + bg) * 4096;
                #pragma unroll
                for (int i = 0; i < 8; ++i) stage16(g + i * 512 + l * 8, &sB2l[0][0][0] + i * 512);
            }
        }

        // x(t+1) register prefetch (kh0 waves; overlaps stage latency)
        f2v xAn = xA, xBn = xB, xCn = xC;
        if (kh == 0 && t + 1 < TT) {
            const float* xnp = xbase + (t + 1) * DDIM;
            xAn = *(const f2v*)(xnp);
            xBn = *(const f2v*)(xnp + 2);
            xCn = *(const f2v*)(xnp + 4);
        }

        __syncthreads();   // stage complete

        // ---- emit out(t-1) from staged LDS slab (emitting WGs only; gg uniform) ----
        if (gg < 16 && t > 0) {
            const hf ehi = __builtin_bit_cast(hf, ((const unsigned short*)sB2h)[eo]);
            const hf elo = __builtin_bit_cast(hf, ((const unsigned short*)sB2l)[eo]);
            const float hval = (float)ehi + LOSC * (float)elo;
            emit_out(hval, Wo, redsc, boV, out + ro * (TT * DDIM) + (t - 1) * DDIM, tid);
        }

        // ---- P5: layer-2; kh0: W_ih2 x h1(t) (sB1), kh1: W_hh2 x h2(t-1) (sB2) ----
        {
            const unsigned short* shp = kh ? &sB2h[0][0][0] : &sB1h[0][0][0];
            const unsigned short* slp = kh ? &sB2l[0][0][0] : &sB1l[0][0][0];
            f4v eA = {0.f,0.f,0.f,0.f}, eB = {0.f,0.f,0.f,0.f}, eC = {0.f,0.f,0.f,0.f};
            #pragma unroll
            for (int c = 0; c < 8; ++c) {
                const h8v vhi = *(const h8v*)(shp + c * 512 + l * 8);
                const h8v vlo = *(const h8v*)(slp + c * 512 + l * 8);
                const h8v Al  = *(const h8v*)&sA2l[wid][c][l][0];
                eA = MFMA(A2h[c], vhi, eA);
                eB = MFMA(A2h[c], vlo, eB);
                eC = MFMA(Al,     vhi, eC);
            }
            const f4v p5 = eA + (eB + eC) * LOSC;
            if (kh) pscrB[gh][l] = p5;
            __syncthreads();
            if (!kh) {
                const f4v acc2 = p5 + pscrB[gh][l];
                const float i2  = sigf(acc2[0] + b2a[0]);
                const float f2g = sigf(acc2[1] + b2a[1]);
                const float g2  = tanhf_fast(acc2[2] + b2a[2]);
                const float o2  = sigf(acc2[3] + b2a[3]);
                c2 = fmaf(f2g, c2, i2 * g2);
                const float h2v = o2 * tanhf_fast(c2);
                hf hh, hl;
                cvt_hl(h2v, hh, hl);
                const int idx = (cur * 16 + bg) * 4096 + so_base;
                st_agent_u16(&B2h[idx], __builtin_bit_cast(unsigned short, hh));
                st_agent_u16(&B2l[idx], __builtin_bit_cast(unsigned short, hl));
            }
        }

        xA = xAn; xB = xBn; xC = xCn;
    }

    // final: publish h2(TT-1), stage, emit
    group_barrier(flags, bg, TT + 1);
    {
        const int curF = (TT - 1) & 1;
        if (wid == 2) {
            const unsigned short* g = B2h + (curF * 16 + bg) * 4096;
            #pragma unroll
            for (int i = 0; i < 8; ++i) stage16(g + i * 512 + l * 8, &sB2h[0][0][0] + i * 512);
        } else if (wid == 3) {
            const unsigned short* g = B2l + (curF * 16 + bg) * 4096;
            #pragma unroll
            for (int i = 0; i < 8; ++i) stage16(g + i * 512 + l * 8, &sB2l[0][0][0] + i * 512);
        }
        __syncthreads();
        if (gg < 16) {
            const hf ehi = __builtin_bit_cast(hf, ((const unsigned short*)sB2h)[eo]);
            const hf elo = __builtin_bit_cast(hf, ((const unsigned short*)sB2l)[eo]);
            const float hval = (float)ehi + LOSC * (float)elo;
            emit_out(hval, Wo, redsc, boV, out + ro * (TT * DDIM) + (TT - 1) * DDIM, tid);
        }
    }
}

extern "C" void kernel_launch(void* const* d_in, const int* in_sizes, int n_in,
                              void* d_out, int out_size, void* d_ws, size_t ws_size,
                              hipStream_t stream) {
    (void)in_sizes; (void)n_in; (void)out_size; (void)ws_size;
    const float* x     = (const float*)d_in[0];
    const float* W_ih1 = (const float*)d_in[1];
    const float* W_hh1 = (const float*)d_in[2];
    const float* b_ih1 = (const float*)d_in[3];
    const float* b_hh1 = (const float*)d_in[4];
    const float* W_ih2 = (const float*)d_in[5];
    const float* W_hh2 = (const float*)d_in[6];
    const float* b_ih2 = (const float*)d_in[7];
    const float* b_hh2 = (const float*)d_in[8];
    const float* W_out = (const float*)d_in[9];
    const float* b_out = (const float*)d_in[10];
    float* out = (float*)d_out;

    char* ws = (char*)d_ws;
    int* flags = (int*)ws;                                        // 512 * 4B = 2KB
    unsigned short* B1h = (unsigned short*)(ws + 2048);           // 256KB each:
    unsigned short* B1l = (unsigned short*)(ws + 2048 + 262144);  // [2][16][4096 u16]
    unsigned short* B2h = (unsigned short*)(ws + 2048 + 524288);
    unsigned short* B2l = (unsigned short*)(ws + 2048 + 786432);

    // only flags need zeroing (slabs fully written before any read)
    hipMemsetAsync(d_ws, 0, 2048, stream);

    hipLaunchKernelGGL(lstm_persist, dim3(512), dim3(256), 0, stream,
                       x, W_ih1, W_hh1, b_ih1, b_hh1,
                       W_ih2, W_hh2, b_ih2, b_hh2,
                       W_out, b_out, out, flags, B1h, B1l, B2h, B2l);
}